// Round 1
// 435.872 us; speedup vs baseline: 1.0166x; 1.0166x over previous
//
#include <hip/hip_runtime.h>
#include <stdint.h>

// Conv: in (32,1,224,224) f32, kernel (64,7,7) f32, pad=3, out (32,64,224,224) f32.
// C=1 stencil as implicit GEMM on MFMA:
//   A = weights (16 filters x K), B = im2col patches (K x 16 pixels),
//   K = 7 rows x 8 (kx padded 7->8, row 7 all-zero weights) = 64 = 2x mfma_f32_16x16x32_f16.
// Input staged in LDS as sliding half2 pairs so each lane's B-fragment
// (8 consecutive kx of one patch row) is 4 aligned dwords at stride 2
// -> 2x ds_read2_b32, conflict-free (2 lanes/bank).
// Per 16-pixel group x 64 filters: 8 MFMA + 8 LDS dwords + 16 stores
// (vs ~900 dot2 + ~900 LDS reads in the previous VALU-bound kernel).

#define H_     224
#define W_     224
#define B_     32
#define F_     64
#define KS_    7
#define TILE   32
#define LROWS  40           // rows staged: r + ky reaches 31+7 = 38
#define LPITCH 40           // sliding-pair slots per row (max used index 37 -> cols 37,38)
#define HW_    (H_ * W_)

typedef _Float16 f16x8 __attribute__((ext_vector_type(8)));
typedef float    f32x4 __attribute__((ext_vector_type(4)));

__global__ __launch_bounds__(256)
void Conv_58394375356438_kernel(const float* __restrict__ in,
                                const float* __restrict__ wt,
                                float* __restrict__ out)
{
    __shared__ uint32_t P[LROWS * LPITCH];   // 6400 B: half2 sliding pairs

    const int blk = blockIdx.x;
    const int tx  = blk % (W_ / TILE);
    const int ty  = (blk / (W_ / TILE)) % (H_ / TILE);
    const int b   = blk / ((W_ / TILE) * (H_ / TILE));
    const int x0  = tx * TILE;
    const int y0  = ty * TILE;

    const float* __restrict__ inp = in + (size_t)b * HW_;

    // ---- Stage input tile + halo as sliding half pairs: P[r*40+j] = (v[j], v[j+1]) ----
    for (int i = threadIdx.x; i < LROWS * LPITCH; i += 256) {
        const int rr = i / LPITCH;
        const int jj = i - rr * LPITCH;
        const int gy = y0 - 3 + rr;
        const int gx = x0 - 3 + jj;
        float v0 = 0.0f, v1 = 0.0f;
        if (gy >= 0 && gy < H_) {
            const float* row = inp + gy * W_;
            if (gx >= 0 && gx < W_)         v0 = row[gx];
            if (gx + 1 >= 0 && gx + 1 < W_) v1 = row[gx + 1];
        }
        union { _Float16 h[2]; uint32_t u; } pk;
        pk.h[0] = (_Float16)v0;            // RNE, matches previous passing kernel
        pk.h[1] = (_Float16)v1;
        P[i] = pk.u;
    }

    // ---- A (weight) fragments, held in registers for the whole block ----
    // mfma_f32_16x16x32_f16 A layout: row m = lane&15 (filter-in-tile),
    // k = (lane>>4)*8 + e  ->  ky = kf*4 + (lane>>4), kx = e (0..7, kx=7 zero).
    const int lane = threadIdx.x & 63;
    const int g    = lane >> 4;
    const int fr   = lane & 15;

    f16x8 afr[4][2];
    #pragma unroll
    for (int t = 0; t < 4; ++t) {
        #pragma unroll
        for (int kf = 0; kf < 2; ++kf) {
            const int ky = kf * 4 + g;
            const float* wrow = wt + (t * 16 + fr) * (KS_ * KS_) + ky * KS_;
            f16x8 a;
            #pragma unroll
            for (int kx = 0; kx < 8; ++kx) {
                const float w = (ky < KS_ && kx < KS_) ? wrow[kx] : 0.0f;
                a[kx] = (_Float16)w;
            }
            afr[t][kf] = a;
        }
    }

    __syncthreads();

    const int wave = threadIdx.x >> 6;   // 4 waves: rows wave*8 .. wave*8+7
    const int p    = lane & 15;          // pixel within 16-wide group (B col, D col)

    // D layout: col = lane&15 = pixel x offset, row = (lane>>4)*4 + j = filter 4g+j.
    float* __restrict__ outbase =
        out + ((size_t)(b * F_ + 4 * g) * H_ + y0) * W_ + x0 + p;

    for (int rr = 0; rr < 8; ++rr) {
        const int r = wave * 8 + rr;
        #pragma unroll
        for (int xb = 0; xb < TILE; xb += 16) {
            // B fragments: lane reads its pixel's patch row (8 halfs) as
            // pairs at cols (xb+p)+{0,2,4,6}; kf=1 is 4 rows further down.
            const int base0 = (r + g) * LPITCH + xb + p;

            union { f16x8 v; uint32_t u[4]; } b0, b1;
            b0.u[0] = P[base0 + 0];
            b0.u[1] = P[base0 + 2];
            b0.u[2] = P[base0 + 4];
            b0.u[3] = P[base0 + 6];
            b1.u[0] = P[base0 + 4 * LPITCH + 0];
            b1.u[1] = P[base0 + 4 * LPITCH + 2];
            b1.u[2] = P[base0 + 4 * LPITCH + 4];
            b1.u[3] = P[base0 + 4 * LPITCH + 6];

            f32x4 acc[4];
            #pragma unroll
            for (int t = 0; t < 4; ++t) acc[t] = (f32x4){0.f, 0.f, 0.f, 0.f};

            #pragma unroll
            for (int t = 0; t < 4; ++t) {
                acc[t] = __builtin_amdgcn_mfma_f32_16x16x32_f16(afr[t][0], b0.v, acc[t], 0, 0, 0);
                acc[t] = __builtin_amdgcn_mfma_f32_16x16x32_f16(afr[t][1], b1.v, acc[t], 0, 0, 0);
            }

            // Store: 16 lanes of a group write 64 contiguous, 64B-aligned bytes
            // per (filter) row; 4 filter rows per store instruction.
            #pragma unroll
            for (int t = 0; t < 4; ++t) {
                #pragma unroll
                for (int j = 0; j < 4; ++j) {
                    outbase[(size_t)(t * 16 + j) * HW_ + r * W_ + xb] = acc[t][j];
                }
            }
        }
    }
}

extern "C" void kernel_launch(void* const* d_in, const int* in_sizes, int n_in,
                              void* d_out, int out_size, void* d_ws, size_t ws_size,
                              hipStream_t stream)
{
    const float* in = (const float*)d_in[0];
    const float* wt = (const float*)d_in[1];
    float* out      = (float*)d_out;

    const int grid = B_ * (H_ / TILE) * (W_ / TILE);   // 1568 blocks, all 64 filters each
    Conv_58394375356438_kernel<<<grid, 256, 0, stream>>>(in, wt, out);
}

// Round 3
// 434.551 us; speedup vs baseline: 1.0197x; 1.0030x over previous
//
#include <hip/hip_runtime.h>
#include <stdint.h>

// Conv: in (32,1,224,224) f32, kernel (64,7,7) f32, pad=3, out (32,64,224,224) f32.
// Implicit GEMM on MFMA with SWAPPED operands: A = im2col patches (16 px x K),
// B = weights^T (K x 16 filters), K = 7 rows x 8 (kx padded, ky=7 zero row) = 64
// = 2x mfma_f32_16x16x32_f16.
// D layout: row = pixel, col = filter -> each lane's 4 accs are 4 CONSECUTIVE x
// of one filter => float4 stores, one wave store = full 16px x 16filt tile (1KB).
// Blocks are full-width row strips (4 rows x 224 px x all 64 filters): per
// (block,filter) the output is one contiguous 3.5KB span, streamed in x ->
// HBM page-local writes. Grid = 32*56 = 1792 = exactly 7 blocks/CU.

#define H_    224
#define W_    224
#define B_    32
#define F_    64
#define KS_   7
#define ROWS  4                 // output rows per block
#define LROWS (ROWS + 7)        // 11 staged rows: gy = y0-3 .. y0+7 (incl. finite ky=7 row)
#define PITCH 232               // dword stride; 232 % 32 = 8 -> bank-conflict-free group offsets
#define HW_   (H_ * W_)

typedef _Float16 f16x8 __attribute__((ext_vector_type(8)));
typedef float    f32x4 __attribute__((ext_vector_type(4)));
typedef uint32_t u32x4 __attribute__((ext_vector_type(4)));

__global__ __launch_bounds__(256)
void Conv_58394375356438_kernel(const float* __restrict__ in,
                                const float* __restrict__ wt,
                                float* __restrict__ out)
{
    __shared__ uint32_t P[LROWS * PITCH];   // 10208 B sliding half2 pairs

    const int blk = blockIdx.x;
    const int yb  = blk % (H_ / ROWS);      // 56 row-strips
    const int b   = blk / (H_ / ROWS);
    const int y0  = yb * ROWS;

    const float* __restrict__ inp = in + (size_t)b * HW_;

    // ---- Stage full-width rows as sliding half pairs: P[lr*PITCH+i] = (v[i-3], v[i-2]) ----
    for (int idx = threadIdx.x; idx < LROWS * PITCH; idx += 256) {
        const int lr = idx / PITCH;
        const int i  = idx - lr * PITCH;
        const int gy = y0 - 3 + lr;
        const int gx = i - 3;
        float v0 = 0.0f, v1 = 0.0f;
        if (gy >= 0 && gy < H_) {
            const float* __restrict__ row = inp + gy * W_;
            if (gx >= 0 && gx < W_)        v0 = row[gx];
            if (gx >= -1 && gx + 1 < W_)   v1 = row[gx + 1];
        }
        union { _Float16 h[2]; uint32_t u; } pk;
        pk.h[0] = (_Float16)v0;            // RNE, matches passing kernels
        pk.h[1] = (_Float16)v1;
        P[idx] = pk.u;
    }

    const int lane = threadIdx.x & 63;
    const int g    = lane >> 4;        // lane group 0..3
    const int fr   = lane & 15;        // filter-in-tile (B col) == pixel-in-tile (A row)

    // B-operand fragments (weights^T): lane holds filter t*16+fr, ky = kf*4+g, kx 0..7.
    f16x8 wfr[4][2];
    #pragma unroll
    for (int t = 0; t < 4; ++t) {
        #pragma unroll
        for (int kf = 0; kf < 2; ++kf) {
            const int ky = kf * 4 + g;
            const float* wrow = wt + (t * 16 + fr) * (KS_ * KS_) + ky * KS_;
            f16x8 a;
            #pragma unroll
            for (int kx = 0; kx < 8; ++kx) {
                const float w = (ky < KS_ && kx < KS_) ? wrow[kx] : 0.0f;
                a[kx] = (_Float16)w;
            }
            wfr[t][kf] = a;
        }
    }

    __syncthreads();

    const int wave = threadIdx.x >> 6;   // wave owns output row y0 + wave
    const int y    = y0 + wave;

    // A-operand (patch) LDS row bases: kf=0 -> patch row wave+g, kf=1 -> +4.
    const uint32_t* __restrict__ p0 = &P[(wave + g) * PITCH];
    const uint32_t* __restrict__ p1 = &P[(wave + g + 4) * PITCH];

    // D: col = fr = filter, row = 4g + j = x offset within the 16-px group.
    float* __restrict__ ob0 = out + ((size_t)(b * F_ +  0 + fr) * H_ + y) * W_ + 4 * g;
    float* __restrict__ ob1 = out + ((size_t)(b * F_ + 16 + fr) * H_ + y) * W_ + 4 * g;
    float* __restrict__ ob2 = out + ((size_t)(b * F_ + 32 + fr) * H_ + y) * W_ + 4 * g;
    float* __restrict__ ob3 = out + ((size_t)(b * F_ + 48 + fr) * H_ + y) * W_ + 4 * g;

    #pragma unroll
    for (int xg = 0; xg < W_ / 16; ++xg) {   // 14 x-groups of 16 px
        const int i0 = xg * 16 + fr;         // lane's pixel column entry
        u32x4 q0, q1;
        q0[0] = p0[i0];     q0[1] = p0[i0 + 2];
        q0[2] = p0[i0 + 4]; q0[3] = p0[i0 + 6];
        q1[0] = p1[i0];     q1[1] = p1[i0 + 2];
        q1[2] = p1[i0 + 4]; q1[3] = p1[i0 + 6];
        const f16x8 pf0 = __builtin_bit_cast(f16x8, q0);
        const f16x8 pf1 = __builtin_bit_cast(f16x8, q1);

        f32x4 a0 = {0.f, 0.f, 0.f, 0.f};
        f32x4 a1 = a0, a2 = a0, a3 = a0;

        a0 = __builtin_amdgcn_mfma_f32_16x16x32_f16(pf0, wfr[0][0], a0, 0, 0, 0);
        a1 = __builtin_amdgcn_mfma_f32_16x16x32_f16(pf0, wfr[1][0], a1, 0, 0, 0);
        a2 = __builtin_amdgcn_mfma_f32_16x16x32_f16(pf0, wfr[2][0], a2, 0, 0, 0);
        a3 = __builtin_amdgcn_mfma_f32_16x16x32_f16(pf0, wfr[3][0], a3, 0, 0, 0);
        a0 = __builtin_amdgcn_mfma_f32_16x16x32_f16(pf1, wfr[0][1], a0, 0, 0, 0);
        a1 = __builtin_amdgcn_mfma_f32_16x16x32_f16(pf1, wfr[1][1], a1, 0, 0, 0);
        a2 = __builtin_amdgcn_mfma_f32_16x16x32_f16(pf1, wfr[2][1], a2, 0, 0, 0);
        a3 = __builtin_amdgcn_mfma_f32_16x16x32_f16(pf1, wfr[3][1], a3, 0, 0, 0);

        *reinterpret_cast<f32x4*>(ob0 + xg * 16) = a0;
        *reinterpret_cast<f32x4*>(ob1 + xg * 16) = a1;
        *reinterpret_cast<f32x4*>(ob2 + xg * 16) = a2;
        *reinterpret_cast<f32x4*>(ob3 + xg * 16) = a3;
    }
}

extern "C" void kernel_launch(void* const* d_in, const int* in_sizes, int n_in,
                              void* d_out, int out_size, void* d_ws, size_t ws_size,
                              hipStream_t stream)
{
    const float* in = (const float*)d_in[0];
    const float* wt = (const float*)d_in[1];
    float* out      = (float*)d_out;

    const int grid = B_ * (H_ / ROWS);   // 32 * 56 = 1792 blocks
    Conv_58394375356438_kernel<<<grid, 256, 0, stream>>>(in, wt, out);
}